// Round 8
// baseline (134.139 us; speedup 1.0000x reference)
//
#include <hip/hip_runtime.h>
#include <math.h>

#define NB 64
#define NN 512
#define ND 128
#define DONE_FLAG 0x1234ABCDu

typedef __attribute__((ext_vector_type(8))) short short8;
typedef __attribute__((ext_vector_type(4))) float f32x4;

// workspace layout (floats)
#define KVB_OFF   0                         // kv bf16: NB*NN*ND ushorts
#define QK_OFF    (NB*NN*ND/2)
#define QSUMP_OFF (QK_OFF + NB*NN)          // NB*4*ND floats
#define FLAG_OFF  (QSUMP_OFF + NB*4*ND)     // 256 uints

__device__ inline unsigned short f2bf(float x) {
    unsigned int u = __float_as_uint(x);
    return (unsigned short)((u + 0x7FFFu + ((u >> 16) & 1u)) >> 16);
}
__device__ inline float bf2f(unsigned short u) {
    return __uint_as_float(((unsigned int)u) << 16);
}

// Single kernel, 256 blocks x 256 threads.
// Phase 1 (block = batch b, row-chunk c): W in-LDS transpose -> MFMA proj ->
//   kvb/qk/qsum_part to global ws -> release flag.
// Handshake: poll the 4 sibling flags of batch b (same-XCD via swizzle).
// Phase 2 (block = batch b, col-group c): agg -> norm -> softmax -> context.
__global__ __launch_bounds__(256, 1) void ga_fused(
    const float* __restrict__ aq, const float* __restrict__ mask,
    const float* __restrict__ Wq, const float* __restrict__ bq,
    const float* __restrict__ Wk, const float* __restrict__ bk,
    unsigned short* __restrict__ kvb, float* __restrict__ qk,
    float* __restrict__ qsum_part, unsigned int* __restrict__ flags,
    float* __restrict__ out_attn, float* __restrict__ out_ctx)
{
    // phase-1 shared (sbuf reused: W stage -> A tile)
    __shared__ __align__(16) unsigned char sbuf[34816];
    unsigned short (*wst)[132] = (unsigned short (*)[132])sbuf;  // [128][132]
    unsigned short (*ast)[136] = (unsigned short (*)[136])sbuf;  // [128][136]
    __shared__ float mask_lds[128];
    __shared__ float qk_part[4][128];
    // phase-2 shared
    __shared__ float qs[128];
    __shared__ float mask_s[512];
    __shared__ float agg_s[512];
    __shared__ float red[8];
    __shared__ float bc2[2];
    __shared__ float zred[4];
    __shared__ float zbc;
    __shared__ float ctx_part[16][33];

    // XCD-aware swizzle: the 4 sibling blocks of a batch share an XCD (p%8
    // heuristic; perf-only — correctness carried by agent-scope fences).
    const int p    = blockIdx.x;
    const int xcd  = p & 7, slot = p >> 3;
    const int b    = ((slot >> 2) << 3) | xcd;   // 0..63
    const int c    = slot & 3;                   // chunk (ph1) / col-group (ph2)
    const int lb   = b*4 + c;                    // logical block id
    const int m0   = c << 7;

    const int t    = threadIdx.x;
    const int w    = t >> 6, lane = t & 63;
    const int quad = lane >> 4, l16 = lane & 15;

    // ================= Phase 1: projection =================
    short8 bfr[4][4];
    #pragma unroll
    for (int s = 0; s < 2; s++) {               // s=0: Wq -> nt 0,1 ; s=1: Wk -> nt 2,3
        const float* Wsrc = s ? Wk : Wq;
        if (s) __syncthreads();                 // protect previous frag reads
        {
            const float4* src = (const float4*)Wsrc;
            #pragma unroll
            for (int i = 0; i < 16; i++) {
                const int idx = t + 256*i;      // 4096 float4 = 16384 floats
                const int row = idx >> 5, c4 = idx & 31;
                const float4 v = src[idx];
                ushort4 o;
                o.x = f2bf(v.x); o.y = f2bf(v.y); o.z = f2bf(v.z); o.w = f2bf(v.w);
                *(ushort4*)&wst[row][c4*4] = o;
            }
        }
        __syncthreads();
        #pragma unroll
        for (int nt = 0; nt < 2; nt++) {
            const int col = w*32 + nt*16 + l16;
            #pragma unroll
            for (int kc = 0; kc < 4; kc++) {
                short8 v;
                #pragma unroll
                for (int j = 0; j < 8; j++)
                    v[j] = (short)wst[kc*32 + quad*8 + j][col];
                bfr[s*2 + nt][kc] = v;
            }
        }
    }
    __syncthreads();

    // stage aq tile fp32 -> bf16 LDS (coalesced float4 reads)
    {
        const float4* src = (const float4*)(aq + ((size_t)b*NN + m0)*ND);
        #pragma unroll
        for (int i = 0; i < 16; i++) {
            const int idx = t + 256*i;
            const int row = idx >> 5, c4 = idx & 31;
            const float4 v = src[idx];
            ushort4 o;
            o.x = f2bf(v.x); o.y = f2bf(v.y); o.z = f2bf(v.z); o.w = f2bf(v.w);
            *(ushort4*)&ast[row][c4*4] = o;
        }
        if (t < 128) mask_lds[t] = mask[b*NN + m0 + t];
    }
    __syncthreads();

    f32x4 acc[8][4];
    #pragma unroll
    for (int m = 0; m < 8; m++)
        #pragma unroll
        for (int nt = 0; nt < 4; nt++)
            acc[m][nt] = (f32x4){0.f, 0.f, 0.f, 0.f};

    #pragma unroll
    for (int m = 0; m < 8; m++) {
        short8 afr[4];
        #pragma unroll
        for (int kc = 0; kc < 4; kc++)
            afr[kc] = *(const short8*)&ast[m*16 + l16][kc*32 + quad*8];
        #pragma unroll
        for (int nt = 0; nt < 4; nt++)
            #pragma unroll
            for (int kc = 0; kc < 4; kc++)
                acc[m][nt] = __builtin_amdgcn_mfma_f32_16x16x32_bf16(
                    afr[kc], bfr[nt][kc], acc[m][nt], 0, 0, 0);
    }

    // bias
    float bv[4];
    #pragma unroll
    for (int nt = 0; nt < 2; nt++) bv[nt] = bq[w*32 + nt*16 + l16];
    #pragma unroll
    for (int nt = 2; nt < 4; nt++) bv[nt] = bk[w*32 + (nt-2)*16 + l16];
    #pragma unroll
    for (int m = 0; m < 8; m++)
        #pragma unroll
        for (int nt = 0; nt < 4; nt++)
            #pragma unroll
            for (int r = 0; r < 4; r++)
                acc[m][nt][r] += bv[nt];

    // store k rows as bf16 (C layout: row = m*16 + quad*4 + r, col = base + l16)
    #pragma unroll
    for (int m = 0; m < 8; m++)
        #pragma unroll
        for (int r = 0; r < 4; r++) {
            const size_t row = (size_t)b*NN + m0 + m*16 + quad*4 + r;
            kvb[row*ND + w*32 + l16]      = f2bf(acc[m][2][r]);
            kvb[row*ND + w*32 + 16 + l16] = f2bf(acc[m][3][r]);
        }

    // qk partial: q.k over this wave's 32 d-cols (full fp32 precision)
    #pragma unroll
    for (int m = 0; m < 8; m++) {
        float pr[4];
        #pragma unroll
        for (int r = 0; r < 4; r++)
            pr[r] = acc[m][0][r]*acc[m][2][r] + acc[m][1][r]*acc[m][3][r];
        #pragma unroll
        for (int off = 1; off <= 8; off <<= 1)
            #pragma unroll
            for (int r = 0; r < 4; r++)
                pr[r] += __shfl_xor(pr[r], off);
        if (l16 == 0)
            #pragma unroll
            for (int r = 0; r < 4; r++)
                qk_part[w][m*16 + quad*4 + r] = pr[r];
    }

    // qsum partial: disjoint slots, plain stores
    {
        float s0 = 0.f, s1 = 0.f;
        #pragma unroll
        for (int m = 0; m < 8; m++)
            #pragma unroll
            for (int r = 0; r < 4; r++) {
                const float mk = mask_lds[m*16 + quad*4 + r];
                s0 += mk * acc[m][0][r];
                s1 += mk * acc[m][1][r];
            }
        s0 += __shfl_xor(s0, 16); s0 += __shfl_xor(s0, 32);
        s1 += __shfl_xor(s1, 16); s1 += __shfl_xor(s1, 32);
        if (quad == 0) {
            const int slotq = lb * ND;
            qsum_part[slotq + w*32 + l16]      = s0;
            qsum_part[slotq + w*32 + 16 + l16] = s1;
        }
    }

    __syncthreads();
    if (t < 128)
        qk[(size_t)b*NN + m0 + t] =
            qk_part[0][t] + qk_part[1][t] + qk_part[2][t] + qk_part[3][t];

    // ============== handshake: release -> poll siblings -> acquire ==============
    __syncthreads();          // all block stores drained (vmcnt at barrier)
    __threadfence();          // agent-scope release (L2 writeback)
    if (t == 0)
        __hip_atomic_store(&flags[lb], DONE_FLAG, __ATOMIC_RELEASE,
                           __HIP_MEMORY_SCOPE_AGENT);
    if (t < 4) {
        while (__hip_atomic_load(&flags[b*4 + t], __ATOMIC_RELAXED,
                                 __HIP_MEMORY_SCOPE_AGENT) != DONE_FLAG)
            __builtin_amdgcn_s_sleep(2);
    }
    __syncthreads();
    __threadfence();          // agent-scope acquire (invalidate stale lines)

    // ================= Phase 2: fused attention =================
    const int cg = c;
    const size_t rowbase = (size_t)b * NN;

    if (t < 128)
        qs[t] = qsum_part[(b*4 + 0)*ND + t] + qsum_part[(b*4 + 1)*ND + t]
              + qsum_part[(b*4 + 2)*ND + t] + qsum_part[(b*4 + 3)*ND + t];
    mask_s[t]       = mask[rowbase + t];
    mask_s[t + 256] = mask[rowbase + t + 256];
    __syncthreads();

    // Phase A: agg[n]; 16 lanes/row (short8 = 8 d each), 4 rows/wave-pass
    {
        float qsf[8];
        #pragma unroll
        for (int j = 0; j < 8; j++) qsf[j] = qs[l16*8 + j];
        for (int i0 = 0; i0 < 128; i0 += 4) {
            const int n = w*128 + i0 + quad;
            const short8 kr = *(const short8*)(kvb + (rowbase + n)*ND + l16*8);
            float pp = 0.f;
            #pragma unroll
            for (int j = 0; j < 8; j++)
                pp += bf2f((unsigned short)kr[j]) * qsf[j];
            #pragma unroll
            for (int off = 1; off <= 8; off <<= 1) pp += __shfl_xor(pp, off);
            if (l16 == 0)
                agg_s[n] = mask_s[n] * (pp - qk[rowbase + n]);
        }
    }
    __syncthreads();

    // Phase B: norm2 + masked max (thread t owns rows t and t+256)
    const float v0 = agg_s[t], v1 = agg_s[t + 256];
    const bool um0 = mask_s[t] != 0.f, um1 = mask_s[t + 256] != 0.f;
    float sq = v0*v0 + v1*v1;
    float mx = fmaxf(um0 ? v0 : -3.0e38f, um1 ? v1 : -3.0e38f);
    #pragma unroll
    for (int off = 1; off <= 32; off <<= 1) {
        sq += __shfl_xor(sq, off);
        mx = fmaxf(mx, __shfl_xor(mx, off));
    }
    if (lane == 0) { red[w] = sq; red[4 + w] = mx; }
    __syncthreads();
    if (t == 0) {
        float s = 0.f, m = -3.0e38f;
        #pragma unroll
        for (int i = 0; i < 4; i++) { s += red[i]; m = fmaxf(m, red[4 + i]); }
        bc2[0] = sqrtf(s);
        bc2[1] = m;
    }
    __syncthreads();
    const float nrm = bc2[0];
    const float M   = bc2[1];

    // Phase C: masked exp + Z
    const float e0 = um0 ? expf((v0 - M) / nrm) : 0.f;
    const float e1 = um1 ? expf((v1 - M) / nrm) : 0.f;
    float z = e0 + e1;
    #pragma unroll
    for (int off = 1; off <= 32; off <<= 1) z += __shfl_xor(z, off);
    if (lane == 0) zred[w] = z;
    agg_s[t] = e0;            // own slots only
    agg_s[t + 256] = e1;
    __syncthreads();
    if (t == 0) zbc = zred[0] + zred[1] + zred[2] + zred[3];
    __syncthreads();
    const float Z = zbc;
    if (cg == 0) {
        out_attn[rowbase + t]       = e0 / Z;
        out_attn[rowbase + t + 256] = e1 / Z;
    }

    // Phase D: context slice, cols [cg*32, cg*32+32); ushort2 loads
    const int c2  = (t & 15) * 2;
    const int col = cg*32 + c2;
    const int rg  = t >> 4;              // 16 row groups
    float a0 = 0.f, a1 = 0.f;
    for (int n = rg; n < NN; n += 16) {
        const ushort2 kk = *(const ushort2*)(kvb + (rowbase + n)*ND + col);
        const float ev = agg_s[n];
        a0 += ev * bf2f(kk.x);
        a1 += ev * bf2f(kk.y);
    }
    ctx_part[rg][c2]     = a0;
    ctx_part[rg][c2 + 1] = a1;
    __syncthreads();
    if (t < 32) {
        float s = 0.f;
        #pragma unroll
        for (int i = 0; i < 16; i++) s += ctx_part[i][t];
        out_ctx[(size_t)b*ND + cg*32 + t] = s / Z;
    }
}

extern "C" void kernel_launch(void* const* d_in, const int* in_sizes, int n_in,
                              void* d_out, int out_size, void* d_ws, size_t ws_size,
                              hipStream_t stream)
{
    const float* aq   = (const float*)d_in[0];
    const float* mask = (const float*)d_in[1];
    const float* Wq   = (const float*)d_in[2];
    const float* bq   = (const float*)d_in[3];
    const float* Wk   = (const float*)d_in[4];
    const float* bk   = (const float*)d_in[5];

    float* ws = (float*)d_ws;
    unsigned short* kvb       = (unsigned short*)(ws + KVB_OFF);
    float*          qk        = ws + QK_OFF;
    float*          qsum_part = ws + QSUMP_OFF;
    unsigned int*   flags     = (unsigned int*)(ws + FLAG_OFF);

    float* out_attn = (float*)d_out;
    float* out_ctx  = (float*)d_out + NB*NN;

    ga_fused<<<dim3(256), dim3(256), 0, stream>>>(aq, mask, Wq, bq, Wk, bk,
                                                  kvb, qk, qsum_part, flags,
                                                  out_attn, out_ctx);
}

// Round 9
// 97.910 us; speedup vs baseline: 1.3700x; 1.3700x over previous
//
#include <hip/hip_runtime.h>
#include <math.h>

#define NB 64
#define NN 512
#define ND 128

typedef __attribute__((ext_vector_type(8))) short short8;
typedef __attribute__((ext_vector_type(4))) float f32x4;

// workspace layout (floats)
#define KVB_OFF   0                         // kv bf16: NB*NN*ND ushorts
#define QKH_OFF   (NB*NN*ND/2)              // qk halves: NB*2*NN floats
#define QSUMP_OFF (QKH_OFF + NB*2*NN)       // qsum partials: NB*8*64 floats

__device__ inline unsigned short f2bf(float x) {
    unsigned int u = __float_as_uint(x);
    return (unsigned short)((u + 0x7FFFu + ((u >> 16) & 1u)) >> 16);
}
__device__ inline float bf2f(unsigned short u) {
    return __uint_as_float(((unsigned int)u) << 16);
}

// K1: bf16 MFMA projection, column-halved. 512 blocks x 256 threads,
// 2 blocks/CU. Block (h, b, rc): 128 rows x (64 q-cols + 64 k-cols), with
// q-col c paired with k-col c so qk stays block-local (emitted as 2 halves).
__global__ __launch_bounds__(256, 2) void proj_mfma(
    const float* __restrict__ aq, const float* __restrict__ mask,
    const float* __restrict__ Wq, const float* __restrict__ bq,
    const float* __restrict__ Wk, const float* __restrict__ bk,
    unsigned short* __restrict__ kvb, float* __restrict__ qkh,
    float* __restrict__ qsum_part)
{
    __shared__ __align__(16) unsigned short wst[128][132]; // cols 0..63 Wq-half, 64..127 Wk-half
    __shared__ __align__(16) unsigned short ast[128][136]; // A tile
    __shared__ float mask_lds[128];
    __shared__ float qk_part[4][128];

    // h = p>>8: the two halves of an (b,rc) tile are 256 apart -> same XCD slot
    const int p    = blockIdx.x;
    const int h    = p >> 8;
    const int rem  = p & 255;
    const int b    = rem >> 2;
    const int rc   = rem & 3;
    const int m0   = rc << 7;

    const int t    = threadIdx.x;
    const int w    = t >> 6, lane = t & 63;
    const int quad = lane >> 4, l16 = lane & 15;

    // ---- stage W halves (fp32, coalesced 256B rows) -> bf16 LDS [k][c] ----
    {
        const float4* srcq = (const float4*)Wq;
        const float4* srck = (const float4*)Wk;
        #pragma unroll
        for (int i = 0; i < 8; i++) {
            const int idx = t + 256*i;          // 2048 float4 per matrix
            const int row = idx >> 4, c4 = idx & 15;
            const int gidx = row*32 + h*16 + c4;
            float4 v = srcq[gidx];
            ushort4 o;
            o.x = f2bf(v.x); o.y = f2bf(v.y); o.z = f2bf(v.z); o.w = f2bf(v.w);
            *(ushort4*)&wst[row][c4*4] = o;
            v = srck[gidx];
            o.x = f2bf(v.x); o.y = f2bf(v.y); o.z = f2bf(v.z); o.w = f2bf(v.w);
            *(ushort4*)&wst[row][64 + c4*4] = o;
        }
    }

    // ---- stage aq tile fp32 -> bf16 LDS (coalesced float4 reads) ----
    {
        const float4* src = (const float4*)(aq + ((size_t)b*NN + m0)*ND);
        #pragma unroll
        for (int i = 0; i < 16; i++) {
            const int idx = t + 256*i;
            const int row = idx >> 5, c4 = idx & 31;
            const float4 v = src[idx];
            ushort4 o;
            o.x = f2bf(v.x); o.y = f2bf(v.y); o.z = f2bf(v.z); o.w = f2bf(v.w);
            *(ushort4*)&ast[row][c4*4] = o;
        }
        if (t < 128) mask_lds[t] = mask[b*NN + m0 + t];
    }
    __syncthreads();     // one barrier covers wst + ast + mask

    // ---- extract B fragments: nt 0 = q cols, nt 1 = k cols (same 16-col slice) ----
    short8 bfr[2][4];
    {
        const int colq = w*16 + l16;
        #pragma unroll
        for (int kc = 0; kc < 4; kc++) {
            short8 vq, vk;
            #pragma unroll
            for (int j = 0; j < 8; j++) {
                vq[j] = (short)wst[kc*32 + quad*8 + j][colq];
                vk[j] = (short)wst[kc*32 + quad*8 + j][64 + colq];
            }
            bfr[0][kc] = vq;
            bfr[1][kc] = vk;
        }
    }
    const float bvq = bq[h*64 + w*16 + l16];
    const float bvk = bk[h*64 + w*16 + l16];

    f32x4 acc[8][2];
    #pragma unroll
    for (int m = 0; m < 8; m++) {
        acc[m][0] = (f32x4){0.f, 0.f, 0.f, 0.f};
        acc[m][1] = (f32x4){0.f, 0.f, 0.f, 0.f};
    }

    #pragma unroll
    for (int m = 0; m < 8; m++) {
        short8 afr[4];
        #pragma unroll
        for (int kc = 0; kc < 4; kc++)
            afr[kc] = *(const short8*)&ast[m*16 + l16][kc*32 + quad*8];
        #pragma unroll
        for (int kc = 0; kc < 4; kc++) {
            acc[m][0] = __builtin_amdgcn_mfma_f32_16x16x32_bf16(
                afr[kc], bfr[0][kc], acc[m][0], 0, 0, 0);
            acc[m][1] = __builtin_amdgcn_mfma_f32_16x16x32_bf16(
                afr[kc], bfr[1][kc], acc[m][1], 0, 0, 0);
        }
    }

    #pragma unroll
    for (int m = 0; m < 8; m++)
        #pragma unroll
        for (int r = 0; r < 4; r++) {
            acc[m][0][r] += bvq;
            acc[m][1][r] += bvk;
        }

    // store k rows as bf16 (C layout: row = m*16 + quad*4 + r)
    {
        const int col = h*64 + w*16 + l16;
        #pragma unroll
        for (int m = 0; m < 8; m++)
            #pragma unroll
            for (int r = 0; r < 4; r++) {
                const size_t row = (size_t)b*NN + m0 + m*16 + quad*4 + r;
                kvb[row*ND + col] = f2bf(acc[m][1][r]);
            }
    }

    // qk half-partial: q.k over this wave's 16 col-pairs (fp32)
    #pragma unroll
    for (int m = 0; m < 8; m++) {
        float pr[4];
        #pragma unroll
        for (int r = 0; r < 4; r++)
            pr[r] = acc[m][0][r] * acc[m][1][r];
        #pragma unroll
        for (int off = 1; off <= 8; off <<= 1)
            #pragma unroll
            for (int r = 0; r < 4; r++)
                pr[r] += __shfl_xor(pr[r], off);
        if (l16 == 0)
            #pragma unroll
            for (int r = 0; r < 4; r++)
                qk_part[w][m*16 + quad*4 + r] = pr[r];
    }

    // qsum partial: disjoint slot per (b, rc, h)
    {
        float s0 = 0.f;
        #pragma unroll
        for (int m = 0; m < 8; m++)
            #pragma unroll
            for (int r = 0; r < 4; r++)
                s0 += mask_lds[m*16 + quad*4 + r] * acc[m][0][r];
        s0 += __shfl_xor(s0, 16); s0 += __shfl_xor(s0, 32);
        if (quad == 0)
            qsum_part[(b*8 + rc*2 + h)*64 + w*16 + l16] = s0;
    }

    __syncthreads();
    if (t < 128)
        qkh[((size_t)b*2 + h)*NN + m0 + t] =
            qk_part[0][t] + qk_part[1][t] + qk_part[2][t] + qk_part[3][t];
}

// K2: fused agg + norm + softmax + context. Grid: b*4 + cg, 512 threads.
__global__ __launch_bounds__(512) void fused_attn(
    const float* __restrict__ mask, const unsigned short* __restrict__ kvb,
    const float* __restrict__ qkh, const float* __restrict__ qsum_part,
    float* __restrict__ out_attn, float* __restrict__ out_ctx)
{
    __shared__ float qs[128];
    __shared__ float mask_s[512];
    __shared__ float agg_s[512];          // then reused to hold e
    __shared__ float red[16];
    __shared__ float bc2[2];
    __shared__ float zred[8];
    __shared__ float zbc;
    __shared__ float ctx_part[32][33];

    const int b  = blockIdx.x >> 2;
    const int cg = blockIdx.x & 3;
    const int t = threadIdx.x, w = t >> 6, lane = t & 63;
    const size_t rowbase = (size_t)b * NN;

    if (t < 128) {
        const int hh = t >> 6, cc = t & 63;
        qs[t] = qsum_part[(b*8 + 0*2 + hh)*64 + cc]
              + qsum_part[(b*8 + 1*2 + hh)*64 + cc]
              + qsum_part[(b*8 + 2*2 + hh)*64 + cc]
              + qsum_part[(b*8 + 3*2 + hh)*64 + cc];
    }
    mask_s[t] = mask[rowbase + t];
    __syncthreads();

    // Phase A: agg[n]; 16 lanes per row (short8 = 8 d each), 4 rows/wave-pass
    const int h16 = lane & 15, quad = lane >> 4;
    float qsf[8];
    #pragma unroll
    for (int j = 0; j < 8; j++) qsf[j] = qs[h16*8 + j];

    for (int i0 = 0; i0 < 64; i0 += 4) {
        const int n = w*64 + i0 + quad;
        const short8 kr = *(const short8*)(kvb + (rowbase + n)*ND + h16*8);
        float pp = 0.f;
        #pragma unroll
        for (int j = 0; j < 8; j++)
            pp += bf2f((unsigned short)kr[j]) * qsf[j];
        #pragma unroll
        for (int off = 1; off <= 8; off <<= 1) pp += __shfl_xor(pp, off);
        if (h16 == 0) {
            const float qkv = qkh[((size_t)b*2 + 0)*NN + n]
                            + qkh[((size_t)b*2 + 1)*NN + n];
            agg_s[n] = mask_s[n] * (pp - qkv);
        }
    }
    __syncthreads();

    // Phase B: norm2 + masked max over 512 rows (thread t owns row t)
    const float v  = agg_s[t];
    const bool um  = mask_s[t] != 0.f;
    float sq = v * v;
    float mx = um ? v : -3.0e38f;
    #pragma unroll
    for (int off = 1; off <= 32; off <<= 1) {
        sq += __shfl_xor(sq, off);
        mx = fmaxf(mx, __shfl_xor(mx, off));
    }
    if (lane == 0) { red[w] = sq; red[8 + w] = mx; }
    __syncthreads();
    if (t == 0) {
        float s = 0.f, m = -3.0e38f;
        #pragma unroll
        for (int i = 0; i < 8; i++) { s += red[i]; m = fmaxf(m, red[8 + i]); }
        bc2[0] = sqrtf(s);
        bc2[1] = m;
    }
    __syncthreads();
    const float nrm = bc2[0];
    const float M   = bc2[1];

    // Phase C: masked exp + Z
    const float e = um ? expf((v - M) / nrm) : 0.f;
    float z = e;
    #pragma unroll
    for (int off = 1; off <= 32; off <<= 1) z += __shfl_xor(z, off);
    if (lane == 0) zred[w] = z;
    agg_s[t] = e;                 // own slot only
    __syncthreads();
    if (t == 0) {
        float s = 0.f;
        #pragma unroll
        for (int i = 0; i < 8; i++) s += zred[i];
        zbc = s;
    }
    __syncthreads();
    const float Z = zbc;
    if (cg == 0) out_attn[rowbase + t] = e / Z;

    // Phase D: context slice, cols [cg*32, cg*32+32); ushort2 loads
    const int c2  = (t & 15) * 2;
    const int col = cg*32 + c2;
    const int rg  = t >> 4;              // 32 row groups
    float a0 = 0.f, a1 = 0.f;
    for (int n = rg; n < NN; n += 32) {
        const ushort2 kk = *(const ushort2*)(kvb + (rowbase + n)*ND + col);
        const float ev = agg_s[n];
        a0 += ev * bf2f(kk.x);
        a1 += ev * bf2f(kk.y);
    }
    ctx_part[rg][c2]     = a0;
    ctx_part[rg][c2 + 1] = a1;
    __syncthreads();
    if (t < 32) {
        float s = 0.f;
        #pragma unroll
        for (int i = 0; i < 32; i++) s += ctx_part[i][t];
        out_ctx[(size_t)b*ND + cg*32 + t] = s / Z;
    }
}

extern "C" void kernel_launch(void* const* d_in, const int* in_sizes, int n_in,
                              void* d_out, int out_size, void* d_ws, size_t ws_size,
                              hipStream_t stream)
{
    const float* aq   = (const float*)d_in[0];
    const float* mask = (const float*)d_in[1];
    const float* Wq   = (const float*)d_in[2];
    const float* bq   = (const float*)d_in[3];
    const float* Wk   = (const float*)d_in[4];
    const float* bk   = (const float*)d_in[5];

    float* ws = (float*)d_ws;
    unsigned short* kvb       = (unsigned short*)(ws + KVB_OFF);
    float*          qkh       = ws + QKH_OFF;
    float*          qsum_part = ws + QSUMP_OFF;

    float* out_attn = (float*)d_out;
    float* out_ctx  = (float*)d_out + NB*NN;

    proj_mfma<<<dim3(512), dim3(256), 0, stream>>>(aq, mask, Wq, bq, Wk, bk,
                                                   kvb, qkh, qsum_part);
    fused_attn<<<dim3(256), dim3(512), 0, stream>>>(mask, kvb, qkh, qsum_part,
                                                    out_attn, out_ctx);
}

// Round 10
// 97.824 us; speedup vs baseline: 1.3712x; 1.0009x over previous
//
#include <hip/hip_runtime.h>
#include <math.h>

#define NB 64
#define NN 512
#define ND 128

typedef __attribute__((ext_vector_type(8))) short short8;
typedef __attribute__((ext_vector_type(4))) float f32x4;

// workspace layout (floats)
#define KVB_OFF   0                         // kv bf16: NB*NN*ND ushorts
#define QK_OFF    (NB*NN*ND/2)
#define QSUMP_OFF (QK_OFF + NB*NN)          // qsum partials: NB*4*ND floats

__device__ inline unsigned short f2bf(float x) {
    unsigned int u = __float_as_uint(x);
    return (unsigned short)((u + 0x7FFFu + ((u >> 16) & 1u)) >> 16);
}
__device__ inline float bf2f(unsigned short u) {
    return __uint_as_float(((unsigned int)u) << 16);
}

// K1: bf16 MFMA projection. 256 blocks x 256 threads; block (b, row-chunk).
// Single-barrier staging: Wq+Wk -> wst[128][266] (extraction conflict-free:
// bank = 8*quad + l16/2), A -> ast[128][132] (66 dwords == 2 mod 32 -> b128
// fragment reads 2-way max = free). 2 barriers total.
__global__ __launch_bounds__(256, 1) void proj_mfma(
    const float* __restrict__ aq, const float* __restrict__ mask,
    const float* __restrict__ Wq, const float* __restrict__ bq,
    const float* __restrict__ Wk, const float* __restrict__ bk,
    unsigned short* __restrict__ kvb, float* __restrict__ qk,
    float* __restrict__ qsum_part)
{
    __shared__ __align__(16) unsigned short wst[128][266]; // shorts 0-127 Wq, 128-255 Wk
    __shared__ __align__(16) unsigned short ast[128][132]; // A tile
    __shared__ float mask_lds[128];
    __shared__ float qk_part[4][128];

    const int b    = blockIdx.x >> 2;
    const int m0   = (blockIdx.x & 3) << 7;
    const int t    = threadIdx.x;
    const int w    = t >> 6, lane = t & 63;
    const int quad = lane >> 4, l16 = lane & 15;

    // ---- stage everything (Wq, Wk, A, mask), all loads in flight, 1 barrier ----
    {
        const float4* srcq = (const float4*)Wq;
        const float4* srck = (const float4*)Wk;
        #pragma unroll
        for (int i = 0; i < 16; i++) {
            const int idx = t + 256*i;          // 4096 float4 per matrix
            const int row = idx >> 5, c4 = idx & 31;
            float4 v = srcq[idx];
            ushort4 o;
            o.x = f2bf(v.x); o.y = f2bf(v.y); o.z = f2bf(v.z); o.w = f2bf(v.w);
            *(ushort4*)&wst[row][c4*4] = o;
            v = srck[idx];
            o.x = f2bf(v.x); o.y = f2bf(v.y); o.z = f2bf(v.z); o.w = f2bf(v.w);
            *(ushort4*)&wst[row][128 + c4*4] = o;
        }
        const float4* srca = (const float4*)(aq + ((size_t)b*NN + m0)*ND);
        #pragma unroll
        for (int i = 0; i < 16; i++) {
            const int idx = t + 256*i;
            const int row = idx >> 5, c4 = idx & 31;
            const float4 v = srca[idx];
            ushort4 o;
            o.x = f2bf(v.x); o.y = f2bf(v.y); o.z = f2bf(v.z); o.w = f2bf(v.w);
            *(ushort4*)&ast[row][c4*4] = o;
        }
        if (t < 128) mask_lds[t] = mask[b*NN + m0 + t];
    }
    __syncthreads();

    // ---- extract B fragments: nt 0,1 = q cols [w*32,+32); nt 2,3 = k cols ----
    short8 bfr[4][4];
    #pragma unroll
    for (int nt = 0; nt < 4; nt++) {
        const int col = ((nt < 2) ? 0 : 128) + w*32 + (nt & 1)*16 + l16;
        #pragma unroll
        for (int kc = 0; kc < 4; kc++) {
            short8 v;
            #pragma unroll
            for (int j = 0; j < 8; j++)
                v[j] = (short)wst[kc*32 + quad*8 + j][col];
            bfr[nt][kc] = v;
        }
    }

    f32x4 acc[8][4];
    #pragma unroll
    for (int m = 0; m < 8; m++)
        #pragma unroll
        for (int nt = 0; nt < 4; nt++)
            acc[m][nt] = (f32x4){0.f, 0.f, 0.f, 0.f};

    #pragma unroll
    for (int m = 0; m < 8; m++) {
        short8 afr[4];
        #pragma unroll
        for (int kc = 0; kc < 4; kc++)
            afr[kc] = *(const short8*)&ast[m*16 + l16][kc*32 + quad*8];
        #pragma unroll
        for (int nt = 0; nt < 4; nt++)
            #pragma unroll
            for (int kc = 0; kc < 4; kc++)
                acc[m][nt] = __builtin_amdgcn_mfma_f32_16x16x32_bf16(
                    afr[kc], bfr[nt][kc], acc[m][nt], 0, 0, 0);
    }

    // bias
    float bv[4];
    #pragma unroll
    for (int nt = 0; nt < 2; nt++) bv[nt] = bq[w*32 + nt*16 + l16];
    #pragma unroll
    for (int nt = 2; nt < 4; nt++) bv[nt] = bk[w*32 + (nt-2)*16 + l16];
    #pragma unroll
    for (int m = 0; m < 8; m++)
        #pragma unroll
        for (int nt = 0; nt < 4; nt++)
            #pragma unroll
            for (int r = 0; r < 4; r++)
                acc[m][nt][r] += bv[nt];

    // store k rows as bf16 (C layout: row = m*16 + quad*4 + r, col = base + l16)
    #pragma unroll
    for (int m = 0; m < 8; m++)
        #pragma unroll
        for (int r = 0; r < 4; r++) {
            const size_t row = (size_t)b*NN + m0 + m*16 + quad*4 + r;
            kvb[row*ND + w*32 + l16]      = f2bf(acc[m][2][r]);
            kvb[row*ND + w*32 + 16 + l16] = f2bf(acc[m][3][r]);
        }

    // qk partial: q.k over this wave's 32 d-cols (full fp32 precision)
    #pragma unroll
    for (int m = 0; m < 8; m++) {
        float pr[4];
        #pragma unroll
        for (int r = 0; r < 4; r++)
            pr[r] = acc[m][0][r]*acc[m][2][r] + acc[m][1][r]*acc[m][3][r];
        #pragma unroll
        for (int off = 1; off <= 8; off <<= 1)
            #pragma unroll
            for (int r = 0; r < 4; r++)
                pr[r] += __shfl_xor(pr[r], off);
        if (l16 == 0)
            #pragma unroll
            for (int r = 0; r < 4; r++)
                qk_part[w][m*16 + quad*4 + r] = pr[r];
    }

    // qsum partial: disjoint slots, plain stores (no atomics, no memset)
    {
        float s0 = 0.f, s1 = 0.f;
        #pragma unroll
        for (int m = 0; m < 8; m++)
            #pragma unroll
            for (int r = 0; r < 4; r++) {
                const float mk = mask_lds[m*16 + quad*4 + r];
                s0 += mk * acc[m][0][r];
                s1 += mk * acc[m][1][r];
            }
        s0 += __shfl_xor(s0, 16); s0 += __shfl_xor(s0, 32);
        s1 += __shfl_xor(s1, 16); s1 += __shfl_xor(s1, 32);
        if (quad == 0) {
            const int slot = blockIdx.x * ND;
            qsum_part[slot + w*32 + l16]      = s0;
            qsum_part[slot + w*32 + 16 + l16] = s1;
        }
    }

    __syncthreads();
    if (t < 128)
        qk[(size_t)b*NN + m0 + t] =
            qk_part[0][t] + qk_part[1][t] + qk_part[2][t] + qk_part[3][t];
}

// K2: fused agg + norm + softmax + context. Grid: b*4 + cg, 512 threads.
// No max-subtraction: logits v/nrm are bounded in [-1,1] since nrm >= |v|.
__global__ __launch_bounds__(512) void fused_attn(
    const float* __restrict__ mask, const unsigned short* __restrict__ kvb,
    const float* __restrict__ qk, const float* __restrict__ qsum_part,
    float* __restrict__ out_attn, float* __restrict__ out_ctx)
{
    __shared__ float qs[128];
    __shared__ float mask_s[512];
    __shared__ float agg_s[512];          // then reused to hold e
    __shared__ float red[8];
    __shared__ float nbc;
    __shared__ float zred[8];
    __shared__ float zbc;
    __shared__ float ctx_part[32][33];

    const int b  = blockIdx.x >> 2;
    const int cg = blockIdx.x & 3;
    const int t = threadIdx.x, w = t >> 6, lane = t & 63;
    const size_t rowbase = (size_t)b * NN;

    if (t < 128)
        qs[t] = qsum_part[(b*4 + 0)*ND + t] + qsum_part[(b*4 + 1)*ND + t]
              + qsum_part[(b*4 + 2)*ND + t] + qsum_part[(b*4 + 3)*ND + t];
    mask_s[t] = mask[rowbase + t];
    __syncthreads();

    // Phase A: agg[n]; 16 lanes per row (short8 = 8 d each), 4 rows/wave-pass
    const int h16 = lane & 15, quad = lane >> 4;
    float qsf[8];
    #pragma unroll
    for (int j = 0; j < 8; j++) qsf[j] = qs[h16*8 + j];

    for (int i0 = 0; i0 < 64; i0 += 4) {
        const int n = w*64 + i0 + quad;
        const short8 kr = *(const short8*)(kvb + (rowbase + n)*ND + h16*8);
        float pp = 0.f;
        #pragma unroll
        for (int j = 0; j < 8; j++)
            pp += bf2f((unsigned short)kr[j]) * qsf[j];
        #pragma unroll
        for (int off = 1; off <= 8; off <<= 1) pp += __shfl_xor(pp, off);
        if (h16 == 0)
            agg_s[n] = mask_s[n] * (pp - qk[rowbase + n]);
    }
    __syncthreads();

    // Phase B: norm2 over 512 rows (thread t owns row t)
    const float v  = agg_s[t];
    const bool um  = mask_s[t] != 0.f;
    float sq = v * v;
    #pragma unroll
    for (int off = 1; off <= 32; off <<= 1) sq += __shfl_xor(sq, off);
    if (lane == 0) red[w] = sq;
    __syncthreads();
    if (t == 0) {
        float s = 0.f;
        #pragma unroll
        for (int i = 0; i < 8; i++) s += red[i];
        nbc = sqrtf(s);
    }
    __syncthreads();
    const float nrm = nbc;

    // Phase C: masked exp + Z  (|v|/nrm <= 1, no max shift needed)
    const float e = um ? expf(v / nrm) : 0.f;
    float z = e;
    #pragma unroll
    for (int off = 1; off <= 32; off <<= 1) z += __shfl_xor(z, off);
    if (lane == 0) zred[w] = z;
    agg_s[t] = e;                 // own slot only
    __syncthreads();
    if (t == 0) {
        float s = 0.f;
        #pragma unroll
        for (int i = 0; i < 8; i++) s += zred[i];
        zbc = s;
    }
    __syncthreads();
    const float Z = zbc;
    if (cg == 0) out_attn[rowbase + t] = e / Z;

    // Phase D: context slice, cols [cg*32, cg*32+32); ushort2 loads
    const int c2  = (t & 15) * 2;
    const int col = cg*32 + c2;
    const int rg  = t >> 4;              // 32 row groups
    float a0 = 0.f, a1 = 0.f;
    for (int n = rg; n < NN; n += 32) {
        const ushort2 kk = *(const ushort2*)(kvb + (rowbase + n)*ND + col);
        const float ev = agg_s[n];
        a0 += ev * bf2f(kk.x);
        a1 += ev * bf2f(kk.y);
    }
    ctx_part[rg][c2]     = a0;
    ctx_part[rg][c2 + 1] = a1;
    __syncthreads();
    if (t < 32) {
        float s = 0.f;
        #pragma unroll
        for (int i = 0; i < 32; i++) s += ctx_part[i][t];
        out_ctx[(size_t)b*ND + cg*32 + t] = s / Z;
    }
}

extern "C" void kernel_launch(void* const* d_in, const int* in_sizes, int n_in,
                              void* d_out, int out_size, void* d_ws, size_t ws_size,
                              hipStream_t stream)
{
    const float* aq   = (const float*)d_in[0];
    const float* mask = (const float*)d_in[1];
    const float* Wq   = (const float*)d_in[2];
    const float* bq   = (const float*)d_in[3];
    const float* Wk   = (const float*)d_in[4];
    const float* bk   = (const float*)d_in[5];

    float* ws = (float*)d_ws;
    unsigned short* kvb       = (unsigned short*)(ws + KVB_OFF);
    float*          qk        = ws + QK_OFF;
    float*          qsum_part = ws + QSUMP_OFF;

    float* out_attn = (float*)d_out;
    float* out_ctx  = (float*)d_out + NB*NN;

    proj_mfma<<<dim3(256), dim3(256), 0, stream>>>(aq, mask, Wq, bq, Wk, bk,
                                                   kvb, qk, qsum_part);
    fused_attn<<<dim3(256), dim3(512), 0, stream>>>(mask, kvb, qk, qsum_part,
                                                    out_attn, out_ctx);
}